// Round 1
// baseline (76.143 us; speedup 1.0000x reference)
//
#include <hip/hip_runtime.h>

// Problem constants (from reference): B=8, N=2048, D=768
#define BB 8
#define NN 2048
#define DD 768
#define BN (BB * NN)          // 16384 rows per tensor
#define ROWS (2 * BN)         // 32768 rows total (H then doc_sents_h)

// Kernel 1: per-row dual dot product.
// One wave (64 lanes) per row. 768 floats = 192 float4 per row = 3 float4/lane.
// ssrc[row] = dot(x_row, W[0:768]) + bias ; sdst[row] = dot(x_row, W[768:1536])
__global__ __launch_bounds__(256) void scores_kernel(
        const float* __restrict__ H,
        const float* __restrict__ Dh,
        const float* __restrict__ W,
        const float* __restrict__ bias,
        float* __restrict__ ssrc,
        float* __restrict__ sdst) {
    const int wave = threadIdx.x >> 6;              // 0..3
    const int lane = threadIdx.x & 63;
    const int row  = blockIdx.x * 4 + wave;         // 0..ROWS-1
    if (row >= ROWS) return;

    const float* x = (row < BN) ? (H + (size_t)row * DD)
                                : (Dh + (size_t)(row - BN) * DD);
    const float4* x4  = reinterpret_cast<const float4*>(x);
    const float4* wa4 = reinterpret_cast<const float4*>(W);
    const float4* wb4 = reinterpret_cast<const float4*>(W + DD);

    float sa = 0.0f, sb = 0.0f;
#pragma unroll
    for (int w = 0; w < 3; ++w) {
        const int idx = lane + w * 64;              // < 192
        const float4 xv = x4[idx];
        const float4 av = wa4[idx];
        const float4 bv = wb4[idx];
        sa += xv.x * av.x + xv.y * av.y + xv.z * av.z + xv.w * av.w;
        sb += xv.x * bv.x + xv.y * bv.y + xv.z * bv.z + xv.w * bv.w;
    }
    // wave64 shuffle reduction
#pragma unroll
    for (int off = 32; off > 0; off >>= 1) {
        sa += __shfl_down(sa, off, 64);
        sb += __shfl_down(sb, off, 64);
    }
    if (lane == 0) {
        ssrc[row] = sa + bias[0];                   // fold bias into src score
        sdst[row] = sb;
    }
}

// Kernel 2: out[row, j] = relu(ssrc[row] + sdst[rowgroup + j]) for j in [0, N)
// One block per output row; 256 threads x 2 float4 each = 2048 floats.
__global__ __launch_bounds__(256) void edges_kernel(
        const float* __restrict__ ssrc,
        const float* __restrict__ sdst,
        float* __restrict__ out) {
    const int row = blockIdx.x;                     // 0..ROWS-1
    const float s = ssrc[row];
    const int group = (row / NN) * NN;              // t*B*N + b*N
    const float4* sd4 = reinterpret_cast<const float4*>(sdst + group);
    float4* o4 = reinterpret_cast<float4*>(out + (size_t)row * NN);

#pragma unroll
    for (int it = 0; it < 2; ++it) {
        const int j4 = threadIdx.x + it * 256;      // < 512
        const float4 d = sd4[j4];
        float4 r;
        r.x = fmaxf(s + d.x, 0.0f);
        r.y = fmaxf(s + d.y, 0.0f);
        r.z = fmaxf(s + d.z, 0.0f);
        r.w = fmaxf(s + d.w, 0.0f);
        o4[j4] = r;
    }
}

extern "C" void kernel_launch(void* const* d_in, const int* in_sizes, int n_in,
                              void* d_out, int out_size, void* d_ws, size_t ws_size,
                              hipStream_t stream) {
    const float* H    = (const float*)d_in[0];
    const float* Dh   = (const float*)d_in[1];
    const float* W    = (const float*)d_in[2];
    const float* bias = (const float*)d_in[3];
    float* out  = (float*)d_out;

    float* ssrc = (float*)d_ws;          // ROWS floats
    float* sdst = ssrc + ROWS;           // ROWS floats  (total 256 KB scratch)

    scores_kernel<<<ROWS / 4, 256, 0, stream>>>(H, Dh, W, bias, ssrc, sdst);
    edges_kernel<<<ROWS, 256, 0, stream>>>(ssrc, sdst, out);
}

// Round 3
// 71.182 us; speedup vs baseline: 1.0697x; 1.0697x over previous
//
#include <hip/hip_runtime.h>

// Problem constants (from reference): B=8, N=2048, D=768
#define BB 8
#define NN 2048
#define DD 768
#define BN (BB * NN)          // 16384 rows per tensor
#define ROWS (2 * BN)         // 32768 rows total (H then doc_sents_h)
#define RPB 16                // rows per block in edges kernel

// clang-native 16B vector (HIP's float4 is a struct the NT builtins reject)
typedef float f4 __attribute__((ext_vector_type(4)));

// Kernel 1: per-row dual dot product.
// One wave (64 lanes) per row. 768 floats = 192 float4 per row = 3 float4/lane.
// ssrc[row] = dot(x_row, W[0:768]) + bias ; sdst[row] = dot(x_row, W[768:1536])
__global__ __launch_bounds__(256) void scores_kernel(
        const float* __restrict__ H,
        const float* __restrict__ Dh,
        const float* __restrict__ W,
        const float* __restrict__ bias,
        float* __restrict__ ssrc,
        float* __restrict__ sdst) {
    const int wave = threadIdx.x >> 6;              // 0..3
    const int lane = threadIdx.x & 63;
    const int row  = blockIdx.x * 4 + wave;         // 0..ROWS-1

    const float* x = (row < BN) ? (H + (size_t)row * DD)
                                : (Dh + (size_t)(row - BN) * DD);
    const f4* x4  = reinterpret_cast<const f4*>(x);
    const f4* wa4 = reinterpret_cast<const f4*>(W);
    const f4* wb4 = reinterpret_cast<const f4*>(W + DD);

    float sa = 0.0f, sb = 0.0f;
#pragma unroll
    for (int w = 0; w < 3; ++w) {
        const int idx = lane + w * 64;              // < 192
        const f4 xv = __builtin_nontemporal_load(&x4[idx]);
        const f4 av = wa4[idx];
        const f4 bv = wb4[idx];
        sa += xv.x * av.x + xv.y * av.y + xv.z * av.z + xv.w * av.w;
        sb += xv.x * bv.x + xv.y * bv.y + xv.z * bv.z + xv.w * bv.w;
    }
    // wave64 shuffle reduction
#pragma unroll
    for (int off = 32; off > 0; off >>= 1) {
        sa += __shfl_down(sa, off, 64);
        sb += __shfl_down(sb, off, 64);
    }
    if (lane == 0) {
        ssrc[row] = sa + bias[0];                   // fold bias into src score
        sdst[row] = sb;
    }
}

// Kernel 2: out[row, j] = relu(ssrc[row] + sdst[group + j]) for j in [0, N)
// 16 rows per block (all in the same batch group). Each thread holds the two
// float4 sdst fragments in registers, then issues 32 nontemporal float4
// stores back-to-back.
__global__ __launch_bounds__(256) void edges_kernel(
        const float* __restrict__ ssrc,
        const float* __restrict__ sdst,
        float* __restrict__ out) {
    const int row0  = blockIdx.x * RPB;             // multiple of 16; NN%16==0
    const int group = (row0 / NN) * NN;
    const f4* sd4 = reinterpret_cast<const f4*>(sdst + group);
    const f4 d0 = sd4[threadIdx.x];
    const f4 d1 = sd4[threadIdx.x + 256];

    float s[RPB];
#pragma unroll
    for (int r = 0; r < RPB; ++r) s[r] = ssrc[row0 + r];

    f4* o4 = reinterpret_cast<f4*>(out + (size_t)row0 * NN);
#pragma unroll
    for (int r = 0; r < RPB; ++r) {
        f4 a, b;
        a.x = fmaxf(s[r] + d0.x, 0.0f);
        a.y = fmaxf(s[r] + d0.y, 0.0f);
        a.z = fmaxf(s[r] + d0.z, 0.0f);
        a.w = fmaxf(s[r] + d0.w, 0.0f);
        b.x = fmaxf(s[r] + d1.x, 0.0f);
        b.y = fmaxf(s[r] + d1.y, 0.0f);
        b.z = fmaxf(s[r] + d1.z, 0.0f);
        b.w = fmaxf(s[r] + d1.w, 0.0f);
        __builtin_nontemporal_store(a, &o4[(size_t)r * 512 + threadIdx.x]);
        __builtin_nontemporal_store(b, &o4[(size_t)r * 512 + threadIdx.x + 256]);
    }
}

extern "C" void kernel_launch(void* const* d_in, const int* in_sizes, int n_in,
                              void* d_out, int out_size, void* d_ws, size_t ws_size,
                              hipStream_t stream) {
    const float* H    = (const float*)d_in[0];
    const float* Dh   = (const float*)d_in[1];
    const float* W    = (const float*)d_in[2];
    const float* bias = (const float*)d_in[3];
    float* out  = (float*)d_out;

    float* ssrc = (float*)d_ws;          // ROWS floats
    float* sdst = ssrc + ROWS;           // ROWS floats  (total 256 KB scratch)

    scores_kernel<<<ROWS / 4, 256, 0, stream>>>(H, Dh, W, bias, ssrc, sdst);
    edges_kernel<<<ROWS / RPB, 256, 0, stream>>>(ssrc, sdst, out);
}